// Round 2
// baseline (1813.034 us; speedup 1.0000x reference)
//
#include <hip/hip_runtime.h>

// receptive_attention: out[b,h,i,j] = (|i-j| <= 128) ? dot(q[i,:], k[j,:]) : 0
// B=2 H=16 L=2048 D=64 fp32. Write-roofline problem: 512 MB mandatory stores.
//
// R1 design: one 256-thread block per (bh, 64-row strip). 1024 blocks = 4/CU
// (35 KB LDS). Per block:
//   - stage Q tile (64x64) once
//   - for each of the 3..5 band K-tiles: stage K, issue 1/nsteps of the
//     out-of-band zero stores (fire-and-forget; drains at next barrier while
//     compute runs), then 4x4-microtile fp32 GEMM + masked band store.
// Micro-tile mapping rows=4a+rr, cols=b+16cc makes K LDS reads hit 16
// consecutive rows (stride 68 floats -> 2-way bank alias, free) and Q reads
// broadcast. Zero volume per block is ~constant -> no straggler blocks.

constexpr int L = 2048;
constexpr int D = 64;
constexpr int R = 128;
constexpr int TILE = 64;
constexpr int NT = L / TILE;   // 32 tiles per dim
constexpr int KS = D + 4;      // LDS row stride 68 floats (16B-aligned, bank-shift 4/row)

__global__ __launch_bounds__(256, 4)
void receptive_attention_kernel(const float* __restrict__ q,
                                const float* __restrict__ k,
                                float* __restrict__ out) {
    const int ti = blockIdx.x;      // 64-row strip index
    const int bh = blockIdx.y;      // batch*head
    const int t  = threadIdx.x;

    const int jt_lo = (ti - 2 > 0) ? (ti - 2) : 0;
    const int jt_hi = (ti + 2 < NT - 1) ? (ti + 2) : (NT - 1);
    const int nsteps = jt_hi - jt_lo + 1;

    __shared__ float Qs[TILE * KS];
    __shared__ float Ks[TILE * KS];

    const float* qT = q + ((size_t)bh * L + (size_t)ti * TILE) * D;
    float* outRow   = out + (size_t)bh * L * L + (size_t)ti * TILE * L;

    // ---- stage Q tile once (64 rows x 64 d), coalesced float4 ----
    #pragma unroll
    for (int it = 0; it < 4; ++it) {
        int idx = t + it * 256;
        int row = idx >> 4, col = (idx & 15) * 4;
        float4 v = *reinterpret_cast<const float4*>(qT + row * D + col);
        float* dst = &Qs[row * KS + col];
        dst[0] = v.x; dst[1] = v.y; dst[2] = v.z; dst[3] = v.w;
    }

    // ---- zero-fill bookkeeping: wave w owns tile rows [16w, 16w+16) ----
    const int lane = t & 63;
    const int w    = t >> 6;
    const int WL4  = jt_lo * (TILE / 4);        // left zero float4s per row
    const int RB   = (jt_hi + 1) * TILE;        // right zero region start col
    const int NZ4  = (L - nsteps * TILE) / 4;   // zero float4s per row
    const int qbase = 16 / nsteps, qrem = 16 % nsteps;
    int zrow = 0;

    const int a = t >> 4;   // row group 0..15  -> rows 4a+rr
    const int b = t & 15;   // col group 0..15  -> cols b+16cc
    const float4 z4 = make_float4(0.f, 0.f, 0.f, 0.f);

    for (int s = 0; s < nsteps; ++s) {
        const int jt = jt_lo + s;
        const float* kT = k + ((size_t)bh * L + (size_t)jt * TILE) * D;

        __syncthreads();   // prev-step Ks readers done (also drains in-flight stores)
        #pragma unroll
        for (int it = 0; it < 4; ++it) {
            int idx = t + it * 256;
            int row = idx >> 4, col = (idx & 15) * 4;
            float4 v = *reinterpret_cast<const float4*>(kT + row * D + col);
            float* dst = &Ks[row * KS + col];
            dst[0] = v.x; dst[1] = v.y; dst[2] = v.z; dst[3] = v.w;
        }
        __syncthreads();   // Ks ready

        // ---- issue this step's share of zero stores (overlaps compute) ----
        int qr = qbase + (s < qrem ? 1 : 0);
        for (int r = 0; r < qr; ++r, ++zrow) {
            float* orow = outRow + (size_t)(w * 16 + zrow) * L;
            for (int f = lane; f < NZ4; f += 64) {
                int col = (f < WL4) ? (f * 4) : (RB + (f - WL4) * 4);
                *reinterpret_cast<float4*>(orow + col) = z4;
            }
        }

        // ---- 4x4 micro-tile fp32 GEMM over d ----
        float acc[4][4] = {};
        #pragma unroll
        for (int dg = 0; dg < 16; ++dg) {
            float4 qa[4], kb[4];
            #pragma unroll
            for (int rr = 0; rr < 4; ++rr)
                qa[rr] = *reinterpret_cast<const float4*>(&Qs[(4 * a + rr) * KS + dg * 4]);
            #pragma unroll
            for (int cc = 0; cc < 4; ++cc)
                kb[cc] = *reinterpret_cast<const float4*>(&Ks[(b + 16 * cc) * KS + dg * 4]);
            #pragma unroll
            for (int rr = 0; rr < 4; ++rr) {
                #pragma unroll
                for (int cc = 0; cc < 4; ++cc) {
                    acc[rr][cc] += qa[rr].x * kb[cc].x + qa[rr].y * kb[cc].y
                                 + qa[rr].z * kb[cc].z + qa[rr].w * kb[cc].w;
                }
            }
        }

        // ---- masked store of this 64x64 band tile ----
        const int j0 = jt * TILE;
        #pragma unroll
        for (int rr = 0; rr < 4; ++rr) {
            const int row = 4 * a + rr;
            const int gi  = ti * TILE + row;
            float* orow = outRow + (size_t)row * L + j0;
            #pragma unroll
            for (int cc = 0; cc < 4; ++cc) {
                const int col = b + 16 * cc;
                int diff = gi - (j0 + col);
                if (diff < 0) diff = -diff;
                orow[col] = (diff <= R) ? acc[rr][cc] : 0.f;
            }
        }
    }
}

extern "C" void kernel_launch(void* const* d_in, const int* in_sizes, int n_in,
                              void* d_out, int out_size, void* d_ws, size_t ws_size,
                              hipStream_t stream) {
    const float* q = (const float*)d_in[0];
    const float* k = (const float*)d_in[1];
    float* out = (float*)d_out;

    dim3 grid(NT, 32);   // (row-strip, b*h) = (32, 32) -> 1024 blocks, 4/CU
    receptive_attention_kernel<<<grid, 256, 0, stream>>>(q, k, out);
}